// Round 4
// baseline (248.254 us; speedup 1.0000x reference)
//
#include <hip/hip_runtime.h>
#include <stdint.h>

// FixedConv1DPriorEnsemble: DZ=30 ensemble of conv nets over embedded tokens.
// V=32000 E=8 DZ=30 C=10, CH=(4,8,8), K=3, S=(2,2,1), B=512, L=4096.
//
// History: R11 318.7 (f16 dot2); R13 256.3 (MFMA stages 2/3); R15 243.4
//   (merged full-sequence blocks); R16 1695 CATASTROPHIC (cross-XCD fence
//   storm); R17 244.3; R18 250.3 (stage-1 MFMA d-paired: occupancy halved,
//   neutral); R19 245.6 (stage-1 MFMA unpaired, occ 83%, ensemble 163);
//   R20 247.9: XCD swizzle cut FETCH 132->16.8MB (!) but ensemble only
//   163->157 -- NOT memory-bound; 8-tok/thread prep embed regressed rest +8.
// R21: issue-count trim + prep revert.
//   (a) prep embed back to 2 tokens/thread, 4096 blocks (R19-proven).
//   (b) stage-1 x loads: 4xb32 -> 2x dwordx2 via aligned(4) vector type
//       (dword-aligned x2 is legal+fast on gfx9+). Halves S1 VMEM instrs.
//   (c) h2 write unconditional: jl=1023 (the only guarded case) feeds only
//       zero-weighted k-slots / pool-masked cols; garbage-finite is safe.
//       Pad-zero moves to [1024,1034) (those are read by masked cols, must
//       not be NaN from stale LDS).

typedef _Float16 f16;
typedef f16 f16x2 __attribute__((ext_vector_type(2)));
typedef f16 f16x4 __attribute__((ext_vector_type(4)));
typedef f16 f16x8 __attribute__((ext_vector_type(8)));
typedef float f32x4 __attribute__((ext_vector_type(4)));
typedef uint32_t u32x2 __attribute__((ext_vector_type(2)));
typedef u32x2 __attribute__((aligned(4))) u32x2_a4;   // dword-aligned dwordx2

#define H1S 2064   // h1 row stride (f16): 1032 dwords (even, ==8 mod 32)
#define H2S 1034   // h2 row stride (f16): 517 dwords, odd mod 32

// ---- prep: embed x_f16 + stage-1/2/3 MFMA A/B-frags ----
__global__ __launch_bounds__(256) void prep_kernel(
    const int* __restrict__ ids, const float* __restrict__ mask,
    const float* __restrict__ tbl,
    const float* __restrict__ W1, const float* __restrict__ W2,
    const float* __restrict__ W3,
    f16* __restrict__ x, f16* __restrict__ a1,
    f16* __restrict__ a2, f16* __restrict__ a3) {
  const int blk = blockIdx.x;
  if (blk < 4096) {                            // embed: 2 tokens/thread
    const int b  = blk >> 3;
    const int l0 = ((blk & 7) * 256 + threadIdx.x) * 2;
    const int2   iv = *(const int2*)(ids + (size_t)b * 4096 + l0);
    const float2 mv = *(const float2*)(mask + (size_t)b * 4096 + l0);
    const float4* t4 = (const float4*)tbl;
    const float4 a0 = t4[(size_t)iv.x * 2], A1 = t4[(size_t)iv.x * 2 + 1];
    const float4 c0 = t4[(size_t)iv.y * 2], C1 = t4[(size_t)iv.y * 2 + 1];
    const float r0[8] = {a0.x, a0.y, a0.z, a0.w, A1.x, A1.y, A1.z, A1.w};
    const float r1[8] = {c0.x, c0.y, c0.z, c0.w, C1.x, C1.y, C1.z, C1.w};
    f16* xb = x + (size_t)b * 8 * 4096 + l0;
    #pragma unroll
    for (int e = 0; e < 8; ++e) {
      f16x2 p; p.x = (f16)(r0[e] * mv.x); p.y = (f16)(r1[e] * mv.y);
      *(f16x2*)(xb + e * 4096) = p;
    }
  } else {
    const int i = (blk - 4096) * 256 + threadIdx.x;
    if (i < 1920) {                            // a1: 30*64
      // Stage-1 B-frag: B[k=kg*8+j][col]; col 0-3 = this d's 4 channels,
      // k -> e=2*kg+(j>>2), tap=j&3 (tap==3 slots zero: K pad 24->32).
      const int d = i >> 6, l = i & 63;
      const int kg = l >> 4, col = l & 15;
      f16x8 v;
      #pragma unroll
      for (int j = 0; j < 8; ++j) {
        const int e = 2 * kg + (j >> 2), tap = j & 3;
        float val = 0.0f;
        if (col < 4 && tap < 3)
          val = W1[d * 96 + col * 24 + e * 3 + tap];
        v[j] = (f16)val;
      }
      *(f16x8*)(a1 + ((size_t)d * 64 + l) * 8) = v;
    } else if (i < 3840) {                     // a2: 30*64
      const int idx = i - 1920, d = idx >> 6, lane = idx & 63;
      const int quad = lane >> 4, m = lane & 15;
      f16x8 v;
      #pragma unroll
      for (int j = 0; j < 8; ++j) {
        float val = 0.0f;
        if (m < 8)  { if (j < 3)           val = W2[d * 96 + m * 12 + quad * 3 + j]; }
        else        { if (j >= 2 && j < 5) val = W2[d * 96 + (m - 8) * 12 + quad * 3 + (j - 2)]; }
        v[j] = (f16)val;
      }
      *(f16x8*)(a2 + ((size_t)d * 64 + lane) * 8) = v;
    } else if (i < 5760) {                     // a3: 30*64
      const int idx = i - 3840, d = idx >> 6, lane = idx & 63;
      const int quad = lane >> 4, m = lane & 15;
      f16x8 v;
      #pragma unroll
      for (int j = 0; j < 8; ++j) {
        const int c2 = quad * 2 + (j >> 2), t = j & 3;
        float val = 0.0f;
        if (m < 8)  { if (t < 3)  val = W3[d * 192 + m * 24 + c2 * 3 + t]; }
        else        { if (t >= 1) val = W3[d * 192 + (m - 8) * 24 + c2 * 3 + (t - 1)]; }
        v[j] = (f16)val;
      }
      *(f16x8*)(a3 + ((size_t)d * 64 + lane) * 8) = v;
    }
  }
}

// ---------------- fast path: one block per (b,d), full sequence ----------------
__global__ __launch_bounds__(256, 8) void ensemble_f16_kernel(
    const f16* __restrict__ x,        // [512][8][4096]
    const f16* __restrict__ a1,       // stage-1 B-frags [30][64][8]
    const f16* __restrict__ a2,       // stage-2 A-frags [30][64][8]
    const f16* __restrict__ a3,       // stage-3 A-frags [30][64][8]
    const float* __restrict__ z,
    const float* __restrict__ b1, const float* __restrict__ b2,
    const float* __restrict__ b3,
    const float* __restrict__ Wh, const float* __restrict__ bh,
    float* __restrict__ part)         // [30][512][10]
{
  const int tid = threadIdx.x;
  // XCD-bijective swizzle: 15360 = 8 XCDs x 1920. All 30 same-b blocks (and
  // 64 consecutive b's) land on one XCD -> x row stays in that XCD's L2.
  const int swz = ((blockIdx.x & 7) * 1920) + (blockIdx.x >> 3);
  const int b   = swz / 30;
  const int d   = swz - b * 30;

  // h1 f16[4][2064] (16512B); h2 f16[8][1034] (16544B) overlays h1.
  __shared__ __align__(16) f16 smemh[8272];
  __shared__ float red[32];
  f16* h1f = smemh;
  f16* h2f = smemh;

  const int w = tid >> 6, lane = tid & 63, quad = lane >> 4, n = tid & 15;

  // zero h1 pads [2048,2064) x 4 rows (stage-2 b64 tiles over-read to 2051);
  // disjoint from stage-1 writes (<=2047), no race.
  if (tid < 64) h1f[(tid >> 4) * H1S + 2048 + (tid & 15)] = (f16)0.0f;

  // ---- stage 1 (MFMA): conv1 (E=8 -> 4ch, K=3, stride 2); 128 tiles ----
  // A = patches: lane(row=n, kg=quad) holds x[e=2q..2q+1][2*pos + 0..3],
  //   pos = 16t + n; tap-3 K-slots hit zero weights (x finite, no masking).
  // B = a1 (cols 0-3 = channels of this d). D: lane(col=n, quad) holds
  //   positions 16t+4*quad+0..3 of channel n (n<4).
  // Write = one b64 per active lane; pos 2047 (t=127,q=3 tail) is written
  //   with a finite garbage conv value: it is only ever multiplied by the
  //   a2 zero k-slots in unmasked outputs (valid stage-2 outputs use
  //   h1 positions <= 2046), so it never affects results.
  {
    const f16x8 bw1 = *(const f16x8*)(a1 + ((size_t)d * 64 + lane) * 8);
    float bias = 0.0f;
    if (n < 4) bias = b1[d * 4 + n];
    const f32x4 c1i = {bias, bias, bias, bias};
    const char* xc = (const char*)(x + (size_t)b * 32768) + quad * 16384 + 4 * n;
    f16x4* h1w = (f16x4*)h1f + n * (H1S / 4);   // n<4 writers only
    #pragma unroll 8
    for (int i = 0; i < 32; ++i) {
      const int t = w + 4 * i;
      const uint32_t o = 64u * (uint32_t)t;
      // e0 taps (2 dwords) + e1 taps (2 dwords): two dword-aligned dwordx2
      const u32x2_a4 lo = *(const u32x2_a4*)(xc + o);         // e0
      const u32x2_a4 hi = *(const u32x2_a4*)(xc + o + 8192);  // e1
      union { f16x8 v; uint32_t dw[4]; } u;
      u.dw[0] = lo[0]; u.dw[1] = lo[1];
      u.dw[2] = hi[0]; u.dw[3] = hi[1];
      const f32x4 D = __builtin_amdgcn_mfma_f32_16x16x32_f16(u.v, bw1, c1i, 0, 0, 0);
      if (n < 4) {
        f16x4 p;
        p.x = (f16)fmaxf(D[0], 0.0f); p.y = (f16)fmaxf(D[1], 0.0f);
        p.z = (f16)fmaxf(D[2], 0.0f); p.w = (f16)fmaxf(D[3], 0.0f);
        h1w[4 * t + quad] = p;                 // f16 ofs 16t+4q, 8B aligned
      }
    }
  }
  __syncthreads();

  // ---- stage 2 (MFMA): rows 0-7 = c2 @ j, rows 8-15 = c2 @ j+1; 32 tiles ----
  f32x4 Ci[8];
  {
    const f16x8 af2 = *(const f16x8*)(a2 + ((size_t)d * 64 + lane) * 8);
    const f32x4 cinit2 = *(const f32x4*)(b2 + d * 8 + (quad & 1) * 4);
    const f16x4* h14 = (const f16x4*)h1f;
    const int qbase = quad * (H1S / 4);
    #pragma unroll
    for (int i = 0; i < 8; ++i) {
      const int t = w + 4 * i;                // 0..31, all valid
      const f16x4 lo = h14[qbase + 16 * t + n];      // ds_read_b64
      const f16x4 hi = h14[qbase + 16 * t + n + 1];  // ds_read_b64
      const f16x8 bv = __builtin_shufflevector(lo, hi, 0, 1, 2, 3, 4, 5, 6, 7);
      Ci[i] = __builtin_amdgcn_mfma_f32_16x16x32_f16(af2, bv, cinit2, 0, 0, 0);
    }
  }
  __syncthreads();               // all h1 reads done; overlay h2

  {
    const int shift = quad >> 1;
    const int c2b   = (quad & 1) * 4;
    #pragma unroll
    for (int i = 0; i < 8; ++i) {
      const int t  = w + 4 * i;
      const int jl = 32 * t + 2 * n + shift;   // <= 1023
      // Unconditional: jl=1023 (t31,n15,s1) is garbage-finite; it feeds only
      // zero-weighted k-slots (valid outputs) or pool-masked cols.
      #pragma unroll
      for (int r = 0; r < 4; ++r)
        h2f[(c2b + r) * H2S + jl] = (f16)fmaxf(Ci[i][r], 0.0f);
    }
    // zero h2 pads [1024,1034) x 8 rows: read (x0-weight or masked-col) but
    // must be finite, not stale-LDS NaN bits.
    if (tid < 80)
      h2f[(tid / 10) * H2S + 1024 + (tid % 10)] = (f16)0.0f;
  }
  __syncthreads();

  // ---- stage 3 (MFMA): rows 0-7 = cc @ p, rows 8-15 = cc @ p+1; pool ----
  float pool4[4] = {0.0f, 0.0f, 0.0f, 0.0f};
  {
    const f16x8 af3 = *(const f16x8*)(a3 + ((size_t)d * 64 + lane) * 8);
    const f32x4 cinit3 = *(const f32x4*)(b3 + d * 8 + (quad & 1) * 4);
    const int c2a = quad * 2;
    #pragma unroll
    for (int i = 0; i < 8; ++i) {
      const int t = w + 4 * i;                // 0..31, all valid
      const f16* bp = h2f + c2a * H2S + 32 * t + 2 * n;
      union { f16x8 v; f16x2 q[4]; } u;
      u.q[0] = *(const f16x2*)bp;
      u.q[1] = *(const f16x2*)(bp + 2);
      u.q[2] = *(const f16x2*)(bp + H2S);
      u.q[3] = *(const f16x2*)(bp + H2S + 2);
      const f32x4 C = __builtin_amdgcn_mfma_f32_16x16x32_f16(af3, u.v, cinit3, 0, 0, 0);
      const int pl = 32 * t + 2 * n + (quad >> 1);
      if (pl < 1021) {
        #pragma unroll
        for (int r = 0; r < 4; ++r) pool4[r] += fmaxf(C[r], 0.0f);
      }
    }
  }

  // ---- pool reduction: shfl_xor butterfly over the 32 lanes sharing a
  //   cc-group (masks 1,2,4,8,32 never touch lane bit 4 = cc-group bit),
  //   then one write per (wave, group) into red[32]; head sums 4 waves.
  {
    #pragma unroll
    for (int r = 0; r < 4; ++r) pool4[r] += __shfl_xor(pool4[r], 1, 64);
    #pragma unroll
    for (int r = 0; r < 4; ++r) pool4[r] += __shfl_xor(pool4[r], 2, 64);
    #pragma unroll
    for (int r = 0; r < 4; ++r) pool4[r] += __shfl_xor(pool4[r], 4, 64);
    #pragma unroll
    for (int r = 0; r < 4; ++r) pool4[r] += __shfl_xor(pool4[r], 8, 64);
    #pragma unroll
    for (int r = 0; r < 4; ++r) pool4[r] += __shfl_xor(pool4[r], 32, 64);
    if ((lane & 47) == 0) {      // lanes 0 (cc 0-3) and 16 (cc 4-7)
      const int g = (lane >> 4) & 1;
      #pragma unroll
      for (int r = 0; r < 4; ++r) red[w * 8 + g * 4 + r] = pool4[r];
    }
  }
  __syncthreads();

  // ---- head ----
  if (tid < 10) {
    float acc = bh[d * 10 + tid];
    #pragma unroll
    for (int c3 = 0; c3 < 8; ++c3) {
      const float pooled = red[c3] + red[8 + c3] + red[16 + c3] + red[24 + c3];
      acc = fmaf(pooled * (1.0f / 1021.0f), Wh[d * 80 + tid * 8 + c3], acc);
    }
    part[((size_t)d * 512 + b) * 10 + tid] = z[d] * acc;
  }
}

// Fixed-order reduction over 30 d-partials: bitwise-deterministic.
__global__ __launch_bounds__(256) void reduce30_kernel(
    const float* __restrict__ part,   // [30][512][10]
    float* __restrict__ out)          // [512][10]
{
  const int i = blockIdx.x * 256 + threadIdx.x;   // 0..5119
  float s = 0.0f;
  #pragma unroll
  for (int dd = 0; dd < 30; ++dd) s += part[dd * 5120 + i];
  out[i] = s;
}

// ---------------- fallback path: exact R7 fp32 kernel (60 partials) ----------------
__global__ __launch_bounds__(256, 6) void ensemble_kernel(
    const int* __restrict__ ids, const float* __restrict__ mask,
    const float* __restrict__ z, const float* __restrict__ tbl,
    const float* __restrict__ W1, const float* __restrict__ b1,
    const float* __restrict__ W2, const float* __restrict__ b2,
    const float* __restrict__ W3, const float* __restrict__ b3,
    const float* __restrict__ Wh, const float* __restrict__ bh,
    float* __restrict__ part)
{
  const int tid  = threadIdx.x;
  const int half = blockIdx.x & 1;
  const int bd   = blockIdx.x >> 1;
  const int b    = bd & 511;
  const int d    = bd >> 9;

  __shared__ float smem[4128];
  __shared__ float red[32];
  __shared__ float pooled[8];

  const int l_lo = half ? 1024 : 0;
  const int l_hi = half ? 2047 : 1029;
  const int j_lo = half ? 512  : 0;
  const int j_hi = half ? 1023 : 514;
  const int o_lo = half ? 512  : 0;
  const int o_hi = half ? 1021 : 512;

  const int*    idrow = ids  + (size_t)b * 4096;
  const float*  mrow  = mask + (size_t)b * 4096;
  const float4* tbl4  = (const float4*)tbl;
  const float*  w1p = W1 + d * 96;
  const float*  w2p = W2 + d * 96;
  const float*  w3p = W3 + d * 192;

  {
    float bia[4];
    #pragma unroll
    for (int c = 0; c < 4; ++c) bia[c] = b1[d * 4 + c];

    #pragma unroll 1
    for (int pass = 0; pass < 2; ++pass) {
      const int l0 = l_lo + 2 * tid + 512 * pass;
      const int p0 = 2 * l0;
      const int4   iv = *(const int4*)(idrow + p0);
      const float4 mv = *(const float4*)(mrow + p0);
      int i4; float m4;
      if (p0 + 4 < 4096) { i4 = idrow[p0 + 4]; m4 = mrow[p0 + 4]; }
      else               { i4 = 0;              m4 = 0.0f; }

      const int   pid[5] = {iv.x, iv.y, iv.z, iv.w, i4};
      const float pm[5]  = {mv.x, mv.y, mv.z, mv.w, m4};

      float a0[4], a1v[4];
      #pragma unroll
      for (int c = 0; c < 4; ++c) { a0[c] = bia[c]; a1v[c] = bia[c]; }

      #pragma unroll
      for (int q = 0; q < 5; ++q) {
        const float4 va = tbl4[(size_t)pid[q] * 2];
        const float4 vb = tbl4[(size_t)pid[q] * 2 + 1];
        const float xe[8] = {va.x * pm[q], va.y * pm[q], va.z * pm[q], va.w * pm[q],
                             vb.x * pm[q], vb.y * pm[q], vb.z * pm[q], vb.w * pm[q]};
        if (q <= 2) {
          #pragma unroll
          for (int c = 0; c < 4; ++c)
            #pragma unroll
            for (int e = 0; e < 8; ++e)
              a0[c] = fmaf(xe[e], w1p[c * 24 + e * 3 + q], a0[c]);
        }
        if (q >= 2) {
          #pragma unroll
          for (int c = 0; c < 4; ++c)
            #pragma unroll
            for (int e = 0; e < 8; ++e)
              a1v[c] = fmaf(xe[e], w1p[c * 24 + e * 3 + (q - 2)], a1v[c]);
        }
      }
      const int rel = l0 - l_lo;
      if (l0 + 1 < l_hi) {
        #pragma unroll
        for (int c = 0; c < 4; ++c)
          *(float2*)(smem + c * 1032 + rel) =
              make_float2(fmaxf(a0[c], 0.0f), fmaxf(a1v[c], 0.0f));
      } else if (l0 < l_hi) {
        #pragma unroll
        for (int c = 0; c < 4; ++c)
          smem[c * 1032 + rel] = fmaxf(a0[c], 0.0f);
      }
    }
    const int lt = l_lo + 1024 + tid;
    if (lt < l_hi) {
      float a0[4];
      #pragma unroll
      for (int c = 0; c < 4; ++c) a0[c] = bia[c];
      #pragma unroll
      for (int k = 0; k < 3; ++k) {
        const int p = 2 * lt + k;
        const int id = idrow[p];
        const float m = mrow[p];
        const float4 va = tbl4[(size_t)id * 2];
        const float4 vb = tbl4[(size_t)id * 2 + 1];
        const float xe[8] = {va.x*m, va.y*m, va.z*m, va.w*m,
                             vb.x*m, vb.y*m, vb.z*m, vb.w*m};
        #pragma unroll
        for (int cc = 0; cc < 4; ++cc)
          #pragma unroll
          for (int e = 0; e < 8; ++e)
            a0[cc] = fmaf(xe[e], w1p[cc * 24 + e * 3 + k], a0[cc]);
      }
      #pragma unroll
      for (int c = 0; c < 4; ++c)
        smem[c * 1032 + 1024 + tid] = fmaxf(a0[c], 0.0f);
    }
  }
  __syncthreads();

  float acc2[8][2], acc2t[8];
  {
    #pragma unroll
    for (int c2 = 0; c2 < 8; ++c2) {
      const float bb = b2[d * 8 + c2];
      acc2[c2][0] = bb; acc2[c2][1] = bb; acc2t[c2] = bb;
    }
    const int rel2  = 4 * tid;
    const bool tail2 = tid < (j_hi - j_lo - 512);
    #pragma unroll 1
    for (int c1 = 0; c1 < 4; ++c1) {
      float sw[8][3];
      #pragma unroll
      for (int c2 = 0; c2 < 8; ++c2)
        #pragma unroll
        for (int kk = 0; kk < 3; ++kk)
          sw[c2][kk] = w2p[c2 * 12 + c1 * 3 + kk];
      const float* hp = smem + c1 * 1032;
      const float4 h01 = *(const float4*)(hp + rel2);
      const float  h4v = hp[rel2 + 4];
      #pragma unroll
      for (int c2 = 0; c2 < 8; ++c2) {
        acc2[c2][0] = fmaf(h01.x, sw[c2][0], fmaf(h01.y, sw[c2][1],
                      fmaf(h01.z, sw[c2][2], acc2[c2][0])));
        acc2[c2][1] = fmaf(h01.z, sw[c2][0], fmaf(h01.w, sw[c2][1],
                      fmaf(h4v,   sw[c2][2], acc2[c2][1])));
      }
      if (tail2) {
        const float t0 = hp[1024 + 2 * tid], t1 = hp[1025 + 2 * tid],
                    t2 = hp[1026 + 2 * tid];
        #pragma unroll
        for (int c2 = 0; c2 < 8; ++c2)
          acc2t[c2] = fmaf(t0, sw[c2][0], fmaf(t1, sw[c2][1],
                      fmaf(t2, sw[c2][2], acc2t[c2])));
      }
    }
    #pragma unroll
    for (int c2 = 0; c2 < 8; ++c2) {
      acc2[c2][0] = fmaxf(acc2[c2][0], 0.0f);
      acc2[c2][1] = fmaxf(acc2[c2][1], 0.0f);
      acc2t[c2]   = fmaxf(acc2t[c2],   0.0f);
    }
    __syncthreads();
    const int j0 = j_lo + 2 * tid;
    const int jr = 2 * tid;
    if (j0 + 1 < j_hi) {
      #pragma unroll
      for (int c2 = 0; c2 < 8; ++c2)
        *(float2*)(smem + c2 * 516 + jr) = make_float2(acc2[c2][0], acc2[c2][1]);
    } else if (j0 < j_hi) {
      #pragma unroll
      for (int c2 = 0; c2 < 8; ++c2)
        smem[c2 * 516 + jr] = acc2[c2][0];
    }
    if (tid < (j_hi - j_lo - 512)) {
      #pragma unroll
      for (int c2 = 0; c2 < 8; ++c2)
        smem[c2 * 516 + 512 + tid] = acc2t[c2];
    }
  }
  __syncthreads();

  float acc3[8][2];
  #pragma unroll
  for (int cc = 0; cc < 8; ++cc) {
    const float bb = b3[d * 8 + cc];
    acc3[cc][0] = bb; acc3[cc][1] = bb;
  }
  {
    const int rel3 = 2 * tid;
    #pragma unroll 1
    for (int c2 = 0; c2 < 8; ++c2) {
      float sw[8][3];
      #pragma unroll
      for (int cc = 0; cc < 8; ++cc)
        #pragma unroll
        for (int kk = 0; kk < 3; ++kk)
          sw[cc][kk] = w3p[cc * 24 + c2 * 3 + kk];
      const float* hp = smem + c2 * 516;
      const float2 ha = *(const float2*)(hp + rel3);
      const float2 hb = *(const float2*)(hp + rel3 + 2);
      #pragma unroll
      for (int cc = 0; cc < 8; ++cc) {
        acc3[cc][0] = fmaf(ha.x, sw[cc][0], fmaf(ha.y, sw[cc][1],
                      fmaf(hb.x, sw[cc][2], acc3[cc][0])));
        acc3[cc][1] = fmaf(ha.y, sw[cc][0], fmaf(hb.x, sw[cc][1],
                      fmaf(hb.y, sw[cc][2], acc3[cc][1])));
      }
    }
  }
  const int i0 = o_lo + 2 * tid;
  float psum[8];
  #pragma unroll
  for (int cc = 0; cc < 8; ++cc) {
    float s = 0.0f;
    if (i0 < o_hi)     s += fmaxf(acc3[cc][0], 0.0f);
    if (i0 + 1 < o_hi) s += fmaxf(acc3[cc][1], 0.0f);
    psum[cc] = s;
  }

  const int lane = tid & 63;
  const int wid  = tid >> 6;
  #pragma unroll
  for (int c = 0; c < 8; ++c) {
    float v = psum[c];
    #pragma unroll
    for (int off = 32; off > 0; off >>= 1) v += __shfl_down(v, off, 64);
    if (lane == 0) red[wid * 8 + c] = v;
  }
  __syncthreads();
  if (tid < 8)
    pooled[tid] = red[tid] + red[8 + tid] + red[16 + tid] + red[24 + tid];
  __syncthreads();

  if (tid < 10) {
    float acc = (half == 0) ? bh[d * 10 + tid] : 0.0f;
    #pragma unroll
    for (int c3 = 0; c3 < 8; ++c3)
      acc = fmaf(pooled[c3] * (1.0f / 1021.0f), Wh[d * 80 + tid * 8 + c3], acc);
    part[(((size_t)d * 2 + half) * 512 + b) * 10 + tid] = z[d] * acc;
  }
}

__global__ __launch_bounds__(256) void reduce60_kernel(
    const float* __restrict__ part,   // [60][512][10]
    float* __restrict__ out)          // [512][10]
{
  const int i = blockIdx.x * 256 + threadIdx.x;
  float s = 0.0f;
  #pragma unroll
  for (int dd = 0; dd < 60; ++dd) s += part[dd * 5120 + i];
  out[i] = s;
}

extern "C" void kernel_launch(void* const* d_in, const int* in_sizes, int n_in,
                              void* d_out, int out_size, void* d_ws, size_t ws_size,
                              hipStream_t stream) {
  const int*   ids  = (const int*)d_in[0];
  const float* mask = (const float*)d_in[1];
  const float* z    = (const float*)d_in[2];
  const float* tbl  = (const float*)d_in[3];
  const float* W1   = (const float*)d_in[4];
  const float* b1   = (const float*)d_in[5];
  const float* W2   = (const float*)d_in[6];
  const float* b2   = (const float*)d_in[7];
  const float* W3   = (const float*)d_in[8];
  const float* b3   = (const float*)d_in[9];
  const float* Wh   = (const float*)d_in[10];
  const float* bh   = (const float*)d_in[11];
  float* out  = (float*)d_out;
  float* part = (float*)d_ws;

  // Layout: part | x | a1 | a2 | a3.  x sits BEFORE the small weight arrays
  // so stage-1's 8-byte tail over-read (b=511,e=7,pos=2047) lands in a1
  // (allocated, finite) instead of past the workspace.
  const size_t part_bytes = 1228800;                       // max(30,60)-layout
  const size_t x_bytes    = (size_t)512 * 8 * 4096 * 2;    // 32 MiB f16
  const size_t a_bytes    = 30720;                         // [30][64][8] f16
  const size_t need = part_bytes + x_bytes + 3 * a_bytes;

  if (ws_size >= need) {
    f16* xh = (f16*)((char*)d_ws + part_bytes);
    f16* a1 = (f16*)((char*)d_ws + part_bytes + x_bytes);
    f16* a2 = (f16*)((char*)d_ws + part_bytes + x_bytes + a_bytes);
    f16* a3 = (f16*)((char*)d_ws + part_bytes + x_bytes + 2 * a_bytes);
    hipLaunchKernelGGL(prep_kernel, dim3(4096 + 23), dim3(256), 0, stream,
                       ids, mask, tbl, W1, W2, W3, xh, a1, a2, a3);
    hipLaunchKernelGGL(ensemble_f16_kernel, dim3(512 * 30), dim3(256), 0, stream,
                       xh, a1, a2, a3, z, b1, b2, b3, Wh, bh, part);
    hipLaunchKernelGGL(reduce30_kernel, dim3(20), dim3(256), 0, stream, part, out);
  } else {
    hipLaunchKernelGGL(ensemble_kernel, dim3(512 * 30 * 2), dim3(256), 0, stream,
                       ids, mask, z, tbl, W1, b1, W2, b2, W3, b3, Wh, bh, part);
    hipLaunchKernelGGL(reduce60_kernel, dim3(20), dim3(256), 0, stream, part, out);
  }
}

// Round 5
// 200.964 us; speedup vs baseline: 1.2353x; 1.2353x over previous
//
#include <hip/hip_runtime.h>
#include <stdint.h>

// FixedConv1DPriorEnsemble: DZ=30 ensemble of conv nets over embedded tokens.
// V=32000 E=8 DZ=30 C=10, CH=(4,8,8), K=3, S=(2,2,1), B=512, L=4096.
//
// History: R15 243.4 best; R16 1695 CATASTROPHIC (cross-XCD fence storm);
//   R18 250.3 (stage-1 MFMA shared per d-pair at 256 thr: LDS 33KB halved
//   occupancy, neutral); R19 245.6 (unpaired, occ 83%, ensemble 163);
//   R20 247.9 (XCD swizzle: FETCH 132->16.8MB but only 163->157 -- NOT
//   memory-bound); R21 248.3 (dwordx2 regressed ensemble to 163.5; VALU
//   47.5% yet no speedup => VALU not critical path; LDS+stage1 mix is).
// R22: d-PAIR at 512 THREADS. R18's stage-1 sharing (halves stage-1 MFMA/
//   VMEM/DS/VALU chip-wide) without its occupancy loss: 512-thread blocks,
//   33KB LDS -> 4 blocks/CU = 32 waves/CU (FULL, vs R18's 16).
//   8 waves: all do stage-1 (16 tiles each, B cols 0-7 = 2d x 4ch);
//   waves 0-3 -> d0, waves 4-7 -> d1 for stages 2/3 in dual LDS regions.
//   Loads reverted to R20's 4xb32 (dwordx2@align4 was the R21 regression).

typedef _Float16 f16;
typedef f16 f16x2 __attribute__((ext_vector_type(2)));
typedef f16 f16x4 __attribute__((ext_vector_type(4)));
typedef f16 f16x8 __attribute__((ext_vector_type(8)));
typedef float f32x4 __attribute__((ext_vector_type(4)));

#define H1S 2064   // h1 row stride (f16): 1032 dwords (even, ==8 mod 32)
#define H2S 1034   // h2 row stride (f16): 517 dwords, odd mod 32
#define REG 8272   // f16 per LDS region: 8*H2S = 8272 >= 4*H1S = 8256

// ---- prep: embed x_f16 + stage-1 pair B-frags + stage-2/3 A-frags ----
__global__ __launch_bounds__(256) void prep_kernel(
    const int* __restrict__ ids, const float* __restrict__ mask,
    const float* __restrict__ tbl,
    const float* __restrict__ W1, const float* __restrict__ W2,
    const float* __restrict__ W3,
    f16* __restrict__ x, f16* __restrict__ a1p,
    f16* __restrict__ a2, f16* __restrict__ a3) {
  const int blk = blockIdx.x;
  if (blk < 4096) {                            // embed: 2 tokens/thread
    const int b  = blk >> 3;
    const int l0 = ((blk & 7) * 256 + threadIdx.x) * 2;
    const int2   iv = *(const int2*)(ids + (size_t)b * 4096 + l0);
    const float2 mv = *(const float2*)(mask + (size_t)b * 4096 + l0);
    const float4* t4 = (const float4*)tbl;
    const float4 a0 = t4[(size_t)iv.x * 2], A1 = t4[(size_t)iv.x * 2 + 1];
    const float4 c0 = t4[(size_t)iv.y * 2], C1 = t4[(size_t)iv.y * 2 + 1];
    const float r0[8] = {a0.x, a0.y, a0.z, a0.w, A1.x, A1.y, A1.z, A1.w};
    const float r1[8] = {c0.x, c0.y, c0.z, c0.w, C1.x, C1.y, C1.z, C1.w};
    f16* xb = x + (size_t)b * 8 * 4096 + l0;
    #pragma unroll
    for (int e = 0; e < 8; ++e) {
      f16x2 p; p.x = (f16)(r0[e] * mv.x); p.y = (f16)(r1[e] * mv.y);
      *(f16x2*)(xb + e * 4096) = p;
    }
  } else {
    const int i = (blk - 4096) * 256 + threadIdx.x;
    if (i < 960) {                             // a1p: 15 pairs * 64 lanes
      // B-frag: B[k=kg*8+j][col]; col 0-7 = (pair half, ch),
      // k -> e=2*kg+(j>>2), tap=j&3 (tap==3 slots zero: K pad 24->32).
      const int g = i >> 6, l = i & 63;
      const int kg = l >> 4, col = l & 15;
      f16x8 v;
      #pragma unroll
      for (int j = 0; j < 8; ++j) {
        const int e = 2 * kg + (j >> 2), tap = j & 3;
        float val = 0.0f;
        if (col < 8 && tap < 3) {
          const int d = g * 2 + (col >> 2), c = col & 3;
          val = W1[d * 96 + c * 24 + e * 3 + tap];
        }
        v[j] = (f16)val;
      }
      *(f16x8*)(a1p + ((size_t)g * 64 + l) * 8) = v;
    } else if (i < 2880) {                     // a2: 30*64
      const int idx = i - 960, d = idx >> 6, lane = idx & 63;
      const int quad = lane >> 4, m = lane & 15;
      f16x8 v;
      #pragma unroll
      for (int j = 0; j < 8; ++j) {
        float val = 0.0f;
        if (m < 8)  { if (j < 3)           val = W2[d * 96 + m * 12 + quad * 3 + j]; }
        else        { if (j >= 2 && j < 5) val = W2[d * 96 + (m - 8) * 12 + quad * 3 + (j - 2)]; }
        v[j] = (f16)val;
      }
      *(f16x8*)(a2 + ((size_t)d * 64 + lane) * 8) = v;
    } else if (i < 4800) {                     // a3: 30*64
      const int idx = i - 2880, d = idx >> 6, lane = idx & 63;
      const int quad = lane >> 4, m = lane & 15;
      f16x8 v;
      #pragma unroll
      for (int j = 0; j < 8; ++j) {
        const int c2 = quad * 2 + (j >> 2), t = j & 3;
        float val = 0.0f;
        if (m < 8)  { if (t < 3)  val = W3[d * 192 + m * 24 + c2 * 3 + t]; }
        else        { if (t >= 1) val = W3[d * 192 + (m - 8) * 24 + c2 * 3 + (t - 1)]; }
        v[j] = (f16)val;
      }
      *(f16x8*)(a3 + ((size_t)d * 64 + lane) * 8) = v;
    }
  }
}

// ------------- fast path: one 512-thread block per (b, d-pair) -------------
__global__ __launch_bounds__(512, 8) void ensemble_f16_kernel(
    const f16* __restrict__ x,        // [512][8][4096]
    const f16* __restrict__ a1p,      // stage-1 B-frags [15][64][8]
    const f16* __restrict__ a2,       // stage-2 A-frags [30][64][8]
    const f16* __restrict__ a3,       // stage-3 A-frags [30][64][8]
    const float* __restrict__ z,
    const float* __restrict__ b1, const float* __restrict__ b2,
    const float* __restrict__ b3,
    const float* __restrict__ Wh, const float* __restrict__ bh,
    float* __restrict__ part)         // [30][512][10]
{
  const int tid = threadIdx.x;
  // XCD-bijective swizzle: 7680 = 8 XCDs x 960. All 15 same-b pair-blocks
  // (and 64 consecutive b's) land on one XCD -> x row lives in its L2.
  const int swz  = ((blockIdx.x & 7) * 960) + (blockIdx.x >> 3);
  const int b    = swz / 15;
  const int pair = swz - b * 15;
  const int d0   = 2 * pair;

  // Two LDS regions (one per d of the pair), 8272 f16 = 16544B each:
  //   h1: f16[4][2064] (16512B) -> overlaid by h2: f16[8][1034] (16544B)
  __shared__ __align__(16) f16 smemh[2 * REG];
  __shared__ float red[2][32];

  const int w = tid >> 6, lane = tid & 63, quad = lane >> 4, n = lane & 15;
  const int g = w >> 2, wv = w & 3;   // d-group (0/1) and wave-in-group
  const int d = d0 + g;

  // zero h1 pads [2048,2064) x 4 rows x 2 regions (stage-2 b64 over-reads
  // to col 2051); disjoint from stage-1 writes (<=2047), no race.
  if (tid < 128)
    smemh[(tid >> 6) * REG + ((tid >> 4) & 3) * H1S + 2048 + (tid & 15)] = (f16)0.0f;

  // ---- stage 1 (MFMA, ALL 8 waves, both d's): 128 tiles of 16 positions ----
  // A = patches: lane(row=n, kg=quad) holds x[e=2q..2q+1][2*pos + 0..3],
  //   pos = 16t + n; tap-3 K-slots hit zero weights (x finite, no masking).
  // B = a1p (cols 0-7 = 2d x 4ch). D: lane(col=n, quad) holds positions
  //   16t+4*quad+0..3 of (d = d0+(n>>2), ch = n&3) for n<8.
  // Position 2047 (t127,q3 tail) is garbage-finite: consumed only by the
  //   masked j=1023 column downstream (valid stage-2 outputs read <=2046).
  {
    const f16x8 bw1 = *(const f16x8*)(a1p + ((size_t)pair * 64 + lane) * 8);
    float bias = 0.0f;
    if (n < 8) bias = b1[(d0 + (n >> 2)) * 4 + (n & 3)];
    const f32x4 c1i = {bias, bias, bias, bias};
    const char* xc = (const char*)(x + (size_t)b * 32768) + quad * 16384 + 4 * n;
    f16x4* h1w = (f16x4*)smemh + (n >> 2) * (REG / 4) + (n & 3) * (H1S / 4) + quad;
    #pragma unroll 8
    for (int i = 0; i < 16; ++i) {
      const int t = w + 8 * i;                 // 0..127
      const uint32_t o = 64u * (uint32_t)t;
      union { f16x8 v; uint32_t dw[4]; } u;
      u.dw[0] = *(const uint32_t*)(xc + o);            // e0: taps 0,1
      u.dw[1] = *(const uint32_t*)(xc + o + 4);        // e0: tap 2 (+dead)
      u.dw[2] = *(const uint32_t*)(xc + o + 8192);     // e1: taps 0,1
      u.dw[3] = *(const uint32_t*)(xc + o + 8192 + 4); // e1: tap 2 (+dead)
      const f32x4 D = __builtin_amdgcn_mfma_f32_16x16x32_f16(u.v, bw1, c1i, 0, 0, 0);
      if (n < 8) {
        f16x4 p;
        p.x = (f16)fmaxf(D[0], 0.0f); p.y = (f16)fmaxf(D[1], 0.0f);
        p.z = (f16)fmaxf(D[2], 0.0f); p.w = (f16)fmaxf(D[3], 0.0f);
        h1w[4 * t] = p;                        // ds_write_b64
      }
    }
  }
  __syncthreads();

  // ---- stage 2 (MFMA): group g handles d = d0+g on its region; 32 tiles ----
  f32x4 Ci[8];
  {
    const f16x8 af2 = *(const f16x8*)(a2 + ((size_t)d * 64 + lane) * 8);
    const f32x4 cinit2 = *(const f32x4*)(b2 + d * 8 + (quad & 1) * 4);
    const f16x4* h14 = (const f16x4*)smemh + g * (REG / 4);
    const int qbase = quad * (H1S / 4);
    #pragma unroll
    for (int i = 0; i < 8; ++i) {
      const int t = wv + 4 * i;               // 0..31
      const f16x4 lo = h14[qbase + 16 * t + n];      // ds_read_b64
      const f16x4 hi = h14[qbase + 16 * t + n + 1];  // ds_read_b64
      const f16x8 bv = __builtin_shufflevector(lo, hi, 0, 1, 2, 3, 4, 5, 6, 7);
      Ci[i] = __builtin_amdgcn_mfma_f32_16x16x32_f16(af2, bv, cinit2, 0, 0, 0);
    }
  }
  __syncthreads();               // all h1 reads done; overlay h2 per region

  {
    f16* h2f = smemh + g * REG;
    const int shift = quad >> 1;
    const int c2b   = (quad & 1) * 4;
    #pragma unroll
    for (int i = 0; i < 8; ++i) {
      const int t  = wv + 4 * i;
      const int jl = 32 * t + 2 * n + shift;   // <= 1023
      // Unconditional: jl=1023 garbage-finite feeds only zero-weighted
      // k-slots (valid outputs) or pool-masked cols.
      #pragma unroll
      for (int r = 0; r < 4; ++r)
        h2f[(c2b + r) * H2S + jl] = (f16)fmaxf(Ci[i][r], 0.0f);
    }
    // zero h2 pads [1024,1034) x 8 rows x 2 regions (finite, not stale LDS)
    if (tid < 160) {
      const int rg = tid / 80, ix = tid - rg * 80;
      smemh[rg * REG + (ix / 10) * H2S + 1024 + (ix % 10)] = (f16)0.0f;
    }
  }
  __syncthreads();

  // ---- stage 3 (MFMA) + pool: group g on its region; 32 tiles ----
  float pool4[4] = {0.0f, 0.0f, 0.0f, 0.0f};
  {
    const f16x8 af3 = *(const f16x8*)(a3 + ((size_t)d * 64 + lane) * 8);
    const f32x4 cinit3 = *(const f32x4*)(b3 + d * 8 + (quad & 1) * 4);
    const f16* h2f = smemh + g * REG;
    const int c2a = quad * 2;
    #pragma unroll
    for (int i = 0; i < 8; ++i) {
      const int t = wv + 4 * i;               // 0..31
      const f16* bp = h2f + c2a * H2S + 32 * t + 2 * n;
      union { f16x8 v; f16x2 q[4]; } u;
      u.q[0] = *(const f16x2*)bp;
      u.q[1] = *(const f16x2*)(bp + 2);
      u.q[2] = *(const f16x2*)(bp + H2S);
      u.q[3] = *(const f16x2*)(bp + H2S + 2);
      const f32x4 C = __builtin_amdgcn_mfma_f32_16x16x32_f16(af3, u.v, cinit3, 0, 0, 0);
      const int pl = 32 * t + 2 * n + (quad >> 1);
      if (pl < 1021) {
        #pragma unroll
        for (int r = 0; r < 4; ++r) pool4[r] += fmaxf(C[r], 0.0f);
      }
    }
  }

  // ---- pool reduction: shfl_xor butterfly over the 32 lanes sharing a
  //   cc-group (masks 1,2,4,8,32 never touch lane bit 4), one write per
  //   (wave, group) into red[g][32]; heads sum the 4 waves of each group.
  {
    #pragma unroll
    for (int r = 0; r < 4; ++r) pool4[r] += __shfl_xor(pool4[r], 1, 64);
    #pragma unroll
    for (int r = 0; r < 4; ++r) pool4[r] += __shfl_xor(pool4[r], 2, 64);
    #pragma unroll
    for (int r = 0; r < 4; ++r) pool4[r] += __shfl_xor(pool4[r], 4, 64);
    #pragma unroll
    for (int r = 0; r < 4; ++r) pool4[r] += __shfl_xor(pool4[r], 8, 64);
    #pragma unroll
    for (int r = 0; r < 4; ++r) pool4[r] += __shfl_xor(pool4[r], 32, 64);
    if ((lane & 47) == 0) {      // lanes 0 (cc 0-3) and 16 (cc 4-7)
      const int cg = (lane >> 4) & 1;
      #pragma unroll
      for (int r = 0; r < 4; ++r) red[g][wv * 8 + cg * 4 + r] = pool4[r];
    }
  }
  __syncthreads();

  // ---- heads: wave 0 -> d0, wave 4 -> d1 ----
  if ((w == 0 || w == 4) && lane < 10) {
    const int gg = w >> 2;
    const int dd = d0 + gg;
    float acc = bh[dd * 10 + lane];
    #pragma unroll
    for (int c3 = 0; c3 < 8; ++c3) {
      const float pooled = red[gg][c3]      + red[gg][8 + c3]
                         + red[gg][16 + c3] + red[gg][24 + c3];
      acc = fmaf(pooled * (1.0f / 1021.0f), Wh[dd * 80 + lane * 8 + c3], acc);
    }
    part[((size_t)dd * 512 + b) * 10 + lane] = z[dd] * acc;
  }
}

// Fixed-order reduction over 30 d-partials: bitwise-deterministic.
__global__ __launch_bounds__(256) void reduce30_kernel(
    const float* __restrict__ part,   // [30][512][10]
    float* __restrict__ out)          // [512][10]
{
  const int i = blockIdx.x * 256 + threadIdx.x;   // 0..5119
  float s = 0.0f;
  #pragma unroll
  for (int dd = 0; dd < 30; ++dd) s += part[dd * 5120 + i];
  out[i] = s;
}

// ---------------- fallback path: exact R7 fp32 kernel (60 partials) ----------------
__global__ __launch_bounds__(256, 6) void ensemble_kernel(
    const int* __restrict__ ids, const float* __restrict__ mask,
    const float* __restrict__ z, const float* __restrict__ tbl,
    const float* __restrict__ W1, const float* __restrict__ b1,
    const float* __restrict__ W2, const float* __restrict__ b2,
    const float* __restrict__ W3, const float* __restrict__ b3,
    const float* __restrict__ Wh, const float* __restrict__ bh,
    float* __restrict__ part)
{
  const int tid  = threadIdx.x;
  const int half = blockIdx.x & 1;
  const int bd   = blockIdx.x >> 1;
  const int b    = bd & 511;
  const int d    = bd >> 9;

  __shared__ float smem[4128];
  __shared__ float red[32];
  __shared__ float pooled[8];

  const int l_lo = half ? 1024 : 0;
  const int l_hi = half ? 2047 : 1029;
  const int j_lo = half ? 512  : 0;
  const int j_hi = half ? 1023 : 514;
  const int o_lo = half ? 512  : 0;
  const int o_hi = half ? 1021 : 512;

  const int*    idrow = ids  + (size_t)b * 4096;
  const float*  mrow  = mask + (size_t)b * 4096;
  const float4* tbl4  = (const float4*)tbl;
  const float*  w1p = W1 + d * 96;
  const float*  w2p = W2 + d * 96;
  const float*  w3p = W3 + d * 192;

  {
    float bia[4];
    #pragma unroll
    for (int c = 0; c < 4; ++c) bia[c] = b1[d * 4 + c];

    #pragma unroll 1
    for (int pass = 0; pass < 2; ++pass) {
      const int l0 = l_lo + 2 * tid + 512 * pass;
      const int p0 = 2 * l0;
      const int4   iv = *(const int4*)(idrow + p0);
      const float4 mv = *(const float4*)(mrow + p0);
      int i4; float m4;
      if (p0 + 4 < 4096) { i4 = idrow[p0 + 4]; m4 = mrow[p0 + 4]; }
      else               { i4 = 0;              m4 = 0.0f; }

      const int   pid[5] = {iv.x, iv.y, iv.z, iv.w, i4};
      const float pm[5]  = {mv.x, mv.y, mv.z, mv.w, m4};

      float a0[4], a1v[4];
      #pragma unroll
      for (int c = 0; c < 4; ++c) { a0[c] = bia[c]; a1v[c] = bia[c]; }

      #pragma unroll
      for (int q = 0; q < 5; ++q) {
        const float4 va = tbl4[(size_t)pid[q] * 2];
        const float4 vb = tbl4[(size_t)pid[q] * 2 + 1];
        const float xe[8] = {va.x * pm[q], va.y * pm[q], va.z * pm[q], va.w * pm[q],
                             vb.x * pm[q], vb.y * pm[q], vb.z * pm[q], vb.w * pm[q]};
        if (q <= 2) {
          #pragma unroll
          for (int c = 0; c < 4; ++c)
            #pragma unroll
            for (int e = 0; e < 8; ++e)
              a0[c] = fmaf(xe[e], w1p[c * 24 + e * 3 + q], a0[c]);
        }
        if (q >= 2) {
          #pragma unroll
          for (int c = 0; c < 4; ++c)
            #pragma unroll
            for (int e = 0; e < 8; ++e)
              a1v[c] = fmaf(xe[e], w1p[c * 24 + e * 3 + (q - 2)], a1v[c]);
        }
      }
      const int rel = l0 - l_lo;
      if (l0 + 1 < l_hi) {
        #pragma unroll
        for (int c = 0; c < 4; ++c)
          *(float2*)(smem + c * 1032 + rel) =
              make_float2(fmaxf(a0[c], 0.0f), fmaxf(a1v[c], 0.0f));
      } else if (l0 < l_hi) {
        #pragma unroll
        for (int c = 0; c < 4; ++c)
          smem[c * 1032 + rel] = fmaxf(a0[c], 0.0f);
      }
    }
    const int lt = l_lo + 1024 + tid;
    if (lt < l_hi) {
      float a0[4];
      #pragma unroll
      for (int c = 0; c < 4; ++c) a0[c] = bia[c];
      #pragma unroll
      for (int k = 0; k < 3; ++k) {
        const int p = 2 * lt + k;
        const int id = idrow[p];
        const float m = mrow[p];
        const float4 va = tbl4[(size_t)id * 2];
        const float4 vb = tbl4[(size_t)id * 2 + 1];
        const float xe[8] = {va.x*m, va.y*m, va.z*m, va.w*m,
                             vb.x*m, vb.y*m, vb.z*m, vb.w*m};
        #pragma unroll
        for (int cc = 0; cc < 4; ++cc)
          #pragma unroll
          for (int e = 0; e < 8; ++e)
            a0[cc] = fmaf(xe[e], w1p[cc * 24 + e * 3 + k], a0[cc]);
      }
      #pragma unroll
      for (int c = 0; c < 4; ++c)
        smem[c * 1032 + 1024 + tid] = fmaxf(a0[c], 0.0f);
    }
  }
  __syncthreads();

  float acc2[8][2], acc2t[8];
  {
    #pragma unroll
    for (int c2 = 0; c2 < 8; ++c2) {
      const float bb = b2[d * 8 + c2];
      acc2[c2][0] = bb; acc2[c2][1] = bb; acc2t[c2] = bb;
    }
    const int rel2  = 4 * tid;
    const bool tail2 = tid < (j_hi - j_lo - 512);
    #pragma unroll 1
    for (int c1 = 0; c1 < 4; ++c1) {
      float sw[8][3];
      #pragma unroll
      for (int c2 = 0; c2 < 8; ++c2)
        #pragma unroll
        for (int kk = 0; kk < 3; ++kk)
          sw[c2][kk] = w2p[c2 * 12 + c1 * 3 + kk];
      const float* hp = smem + c1 * 1032;
      const float4 h01 = *(const float4*)(hp + rel2);
      const float  h4v = hp[rel2 + 4];
      #pragma unroll
      for (int c2 = 0; c2 < 8; ++c2) {
        acc2[c2][0] = fmaf(h01.x, sw[c2][0], fmaf(h01.y, sw[c2][1],
                      fmaf(h01.z, sw[c2][2], acc2[c2][0])));
        acc2[c2][1] = fmaf(h01.z, sw[c2][0], fmaf(h01.w, sw[c2][1],
                      fmaf(h4v,   sw[c2][2], acc2[c2][1])));
      }
      if (tail2) {
        const float t0 = hp[1024 + 2 * tid], t1 = hp[1025 + 2 * tid],
                    t2 = hp[1026 + 2 * tid];
        #pragma unroll
        for (int c2 = 0; c2 < 8; ++c2)
          acc2t[c2] = fmaf(t0, sw[c2][0], fmaf(t1, sw[c2][1],
                      fmaf(t2, sw[c2][2], acc2t[c2])));
      }
    }
    #pragma unroll
    for (int c2 = 0; c2 < 8; ++c2) {
      acc2[c2][0] = fmaxf(acc2[c2][0], 0.0f);
      acc2[c2][1] = fmaxf(acc2[c2][1], 0.0f);
      acc2t[c2]   = fmaxf(acc2t[c2],   0.0f);
    }
    __syncthreads();
    const int j0 = j_lo + 2 * tid;
    const int jr = 2 * tid;
    if (j0 + 1 < j_hi) {
      #pragma unroll
      for (int c2 = 0; c2 < 8; ++c2)
        *(float2*)(smem + c2 * 516 + jr) = make_float2(acc2[c2][0], acc2[c2][1]);
    } else if (j0 < j_hi) {
      #pragma unroll
      for (int c2 = 0; c2 < 8; ++c2)
        smem[c2 * 516 + jr] = acc2[c2][0];
    }
    if (tid < (j_hi - j_lo - 512)) {
      #pragma unroll
      for (int c2 = 0; c2 < 8; ++c2)
        smem[c2 * 516 + 512 + tid] = acc2t[c2];
    }
  }
  __syncthreads();

  float acc3[8][2];
  #pragma unroll
  for (int cc = 0; cc < 8; ++cc) {
    const float bb = b3[d * 8 + cc];
    acc3[cc][0] = bb; acc3[cc][1] = bb;
  }
  {
    const int rel3 = 2 * tid;
    #pragma unroll 1
    for (int c2 = 0; c2 < 8; ++c2) {
      float sw[8][3];
      #pragma unroll
      for (int cc = 0; cc < 8; ++cc)
        #pragma unroll
        for (int kk = 0; kk < 3; ++kk)
          sw[cc][kk] = w3p[cc * 24 + c2 * 3 + kk];
      const float* hp = smem + c2 * 516;
      const float2 ha = *(const float2*)(hp + rel3);
      const float2 hb = *(const float2*)(hp + rel3 + 2);
      #pragma unroll
      for (int cc = 0; cc < 8; ++cc) {
        acc3[cc][0] = fmaf(ha.x, sw[cc][0], fmaf(ha.y, sw[cc][1],
                      fmaf(hb.x, sw[cc][2], acc3[cc][0])));
        acc3[cc][1] = fmaf(ha.y, sw[cc][0], fmaf(hb.x, sw[cc][1],
                      fmaf(hb.y, sw[cc][2], acc3[cc][1])));
      }
    }
  }
  const int i0 = o_lo + 2 * tid;
  float psum[8];
  #pragma unroll
  for (int cc = 0; cc < 8; ++cc) {
    float s = 0.0f;
    if (i0 < o_hi)     s += fmaxf(acc3[cc][0], 0.0f);
    if (i0 + 1 < o_hi) s += fmaxf(acc3[cc][1], 0.0f);
    psum[cc] = s;
  }

  const int lane = tid & 63;
  const int wid  = tid >> 6;
  #pragma unroll
  for (int c = 0; c < 8; ++c) {
    float v = psum[c];
    #pragma unroll
    for (int off = 32; off > 0; off >>= 1) v += __shfl_down(v, off, 64);
    if (lane == 0) red[wid * 8 + c] = v;
  }
  __syncthreads();
  if (tid < 8)
    pooled[tid] = red[tid] + red[8 + tid] + red[16 + tid] + red[24 + tid];
  __syncthreads();

  if (tid < 10) {
    float acc = (half == 0) ? bh[d * 10 + tid] : 0.0f;
    #pragma unroll
    for (int c3 = 0; c3 < 8; ++c3)
      acc = fmaf(pooled[c3] * (1.0f / 1021.0f), Wh[d * 80 + tid * 8 + c3], acc);
    part[(((size_t)d * 2 + half) * 512 + b) * 10 + tid] = z[d] * acc;
  }
}

__global__ __launch_bounds__(256) void reduce60_kernel(
    const float* __restrict__ part,   // [60][512][10]
    float* __restrict__ out)          // [512][10]
{
  const int i = blockIdx.x * 256 + threadIdx.x;
  float s = 0.0f;
  #pragma unroll
  for (int dd = 0; dd < 60; ++dd) s += part[dd * 5120 + i];
  out[i] = s;
}

extern "C" void kernel_launch(void* const* d_in, const int* in_sizes, int n_in,
                              void* d_out, int out_size, void* d_ws, size_t ws_size,
                              hipStream_t stream) {
  const int*   ids  = (const int*)d_in[0];
  const float* mask = (const float*)d_in[1];
  const float* z    = (const float*)d_in[2];
  const float* tbl  = (const float*)d_in[3];
  const float* W1   = (const float*)d_in[4];
  const float* b1   = (const float*)d_in[5];
  const float* W2   = (const float*)d_in[6];
  const float* b2   = (const float*)d_in[7];
  const float* W3   = (const float*)d_in[8];
  const float* b3   = (const float*)d_in[9];
  const float* Wh   = (const float*)d_in[10];
  const float* bh   = (const float*)d_in[11];
  float* out  = (float*)d_out;
  float* part = (float*)d_ws;

  // Layout: part | x | a1p | a2 | a3.  x sits BEFORE the small weight arrays
  // so stage-1's 4-byte tail over-read (b=511,e=7,pos=2047) lands in a1p
  // (allocated, finite) instead of past the workspace.
  const size_t part_bytes = 1228800;                       // max(30,60)-layout
  const size_t x_bytes    = (size_t)512 * 8 * 4096 * 2;    // 32 MiB f16
  const size_t a1_bytes   = 15360;                         // [15][64][8] f16
  const size_t a_bytes    = 30720;                         // [30][64][8] f16
  const size_t need = part_bytes + x_bytes + a1_bytes + 2 * a_bytes;

  if (ws_size >= need) {
    f16* xh  = (f16*)((char*)d_ws + part_bytes);
    f16* a1p = (f16*)((char*)d_ws + part_bytes + x_bytes);
    f16* a2  = (f16*)((char*)d_ws + part_bytes + x_bytes + a1_bytes);
    f16* a3  = (f16*)((char*)d_ws + part_bytes + x_bytes + a1_bytes + a_bytes);
    hipLaunchKernelGGL(prep_kernel, dim3(4096 + 19), dim3(256), 0, stream,
                       ids, mask, tbl, W1, W2, W3, xh, a1p, a2, a3);
    hipLaunchKernelGGL(ensemble_f16_kernel, dim3(512 * 15), dim3(512), 0, stream,
                       xh, a1p, a2, a3, z, b1, b2, b3, Wh, bh, part);
    hipLaunchKernelGGL(reduce30_kernel, dim3(20), dim3(256), 0, stream, part, out);
  } else {
    hipLaunchKernelGGL(ensemble_kernel, dim3(512 * 30 * 2), dim3(256), 0, stream,
                       ids, mask, z, tbl, W1, b1, W2, b2, W3, b3, Wh, bh, part);
    hipLaunchKernelGGL(reduce60_kernel, dim3(20), dim3(256), 0, stream, part, out);
  }
}

// Round 6
// 187.235 us; speedup vs baseline: 1.3259x; 1.0733x over previous
//
#include <hip/hip_runtime.h>
#include <stdint.h>

// FixedConv1DPriorEnsemble: DZ=30 ensemble of conv nets over embedded tokens.
// V=32000 E=8 DZ=30 C=10, CH=(4,8,8), K=3, S=(2,2,1), B=512, L=4096.
//
// History: R15 243.4; R16 1695 CATASTROPHIC (cross-XCD fences); R19 245.6
//   (stage-1 MFMA unpaired); R20 247.9 (XCD swizzle: FETCH 132->16.8MB, not
//   mem-bound); R21 248.3 (dwordx2 regression); R22 201.0 (d-PAIR @512thr:
//   stage-1 shared by 2 nets, ensemble 163->112, occ 80%).
// R23: d-QUAD @1024thr. Stage-1 B uses all 16 MFMA columns (4d x 4ch) ->
//   stage-1 MFMA/VMEM/DS halve again (tiles/b 1920->1024). LDS: 4 regions
//   x 8192 f16 = exactly 64KB via power-of-2 strides H1S=2048/H2S=1024 +
//   per-row rotation swizzle slot=(p+5*row)&511 (bijective per row; keeps
//   b64/b32 near bank floor; boundary over-reads wrap to in-bounds finite
//   data feeding only zero-weighted K-slots or masked cols). red[] overlays
//   region 0 post-barrier. 2 blocks/CU x 16 waves = 32 waves/CU full occ.
//   Grid 512 x 8 groups (7 quads + 1 pair-tail: d clamped to 29 for loads,
//   part writes guarded d<30; tail h1 regions 2/3 = finite bias constants).

typedef _Float16 f16;
typedef f16 f16x2 __attribute__((ext_vector_type(2)));
typedef f16 f16x4 __attribute__((ext_vector_type(4)));
typedef f16 f16x8 __attribute__((ext_vector_type(8)));
typedef float f32x4 __attribute__((ext_vector_type(4)));

// ---- prep: embed x_f16 + stage-1 quad B-frags + stage-2/3 A-frags ----
__global__ __launch_bounds__(256) void prep_kernel(
    const int* __restrict__ ids, const float* __restrict__ mask,
    const float* __restrict__ tbl,
    const float* __restrict__ W1, const float* __restrict__ W2,
    const float* __restrict__ W3,
    f16* __restrict__ x, f16* __restrict__ a1q,
    f16* __restrict__ a2, f16* __restrict__ a3) {
  const int blk = blockIdx.x;
  if (blk < 4096) {                            // embed: 2 tokens/thread
    const int b  = blk >> 3;
    const int l0 = ((blk & 7) * 256 + threadIdx.x) * 2;
    const int2   iv = *(const int2*)(ids + (size_t)b * 4096 + l0);
    const float2 mv = *(const float2*)(mask + (size_t)b * 4096 + l0);
    const float4* t4 = (const float4*)tbl;
    const float4 a0 = t4[(size_t)iv.x * 2], A1 = t4[(size_t)iv.x * 2 + 1];
    const float4 c0 = t4[(size_t)iv.y * 2], C1 = t4[(size_t)iv.y * 2 + 1];
    const float r0[8] = {a0.x, a0.y, a0.z, a0.w, A1.x, A1.y, A1.z, A1.w};
    const float r1[8] = {c0.x, c0.y, c0.z, c0.w, C1.x, C1.y, C1.z, C1.w};
    f16* xb = x + (size_t)b * 8 * 4096 + l0;
    #pragma unroll
    for (int e = 0; e < 8; ++e) {
      f16x2 p; p.x = (f16)(r0[e] * mv.x); p.y = (f16)(r1[e] * mv.y);
      *(f16x2*)(xb + e * 4096) = p;
    }
  } else {
    const int i = (blk - 4096) * 256 + threadIdx.x;
    if (i < 512) {                             // a1q: 8 groups * 64 lanes
      // Stage-1 B-frag: B[k=kg*8+j][col]; col 0-15 = (d_off, ch) for the
      // quad d = 4g+d_off; k -> e=2*kg+(j>>2), tap=j&3 (tap==3 slots zero).
      const int g = i >> 6, l = i & 63;
      const int kg = l >> 4, col = l & 15;
      const int d = 4 * g + (col >> 2);
      f16x8 v;
      #pragma unroll
      for (int j = 0; j < 8; ++j) {
        const int e = 2 * kg + (j >> 2), tap = j & 3;
        float val = 0.0f;
        if (tap < 3 && d < 30)
          val = W1[d * 96 + (col & 3) * 24 + e * 3 + tap];
        v[j] = (f16)val;
      }
      *(f16x8*)(a1q + ((size_t)g * 64 + l) * 8) = v;
    } else if (i < 2432) {                     // a2: 30*64
      const int idx = i - 512, d = idx >> 6, lane = idx & 63;
      const int quad = lane >> 4, m = lane & 15;
      f16x8 v;
      #pragma unroll
      for (int j = 0; j < 8; ++j) {
        float val = 0.0f;
        if (m < 8)  { if (j < 3)           val = W2[d * 96 + m * 12 + quad * 3 + j]; }
        else        { if (j >= 2 && j < 5) val = W2[d * 96 + (m - 8) * 12 + quad * 3 + (j - 2)]; }
        v[j] = (f16)val;
      }
      *(f16x8*)(a2 + ((size_t)d * 64 + lane) * 8) = v;
    } else if (i < 4352) {                     // a3: 30*64
      const int idx = i - 2432, d = idx >> 6, lane = idx & 63;
      const int quad = lane >> 4, m = lane & 15;
      f16x8 v;
      #pragma unroll
      for (int j = 0; j < 8; ++j) {
        const int c2 = quad * 2 + (j >> 2), t = j & 3;
        float val = 0.0f;
        if (m < 8)  { if (t < 3)  val = W3[d * 192 + m * 24 + c2 * 3 + t]; }
        else        { if (t >= 1) val = W3[d * 192 + (m - 8) * 24 + c2 * 3 + (t - 1)]; }
        v[j] = (f16)val;
      }
      *(f16x8*)(a3 + ((size_t)d * 64 + lane) * 8) = v;
    }
  }
}

// ---------- fast path: one 1024-thread block per (b, d-quad group) ----------
__global__ __launch_bounds__(1024, 8) void ensemble_f16_kernel(
    const f16* __restrict__ x,        // [512][8][4096]
    const f16* __restrict__ a1q,      // stage-1 B-frags [8][64][8]
    const f16* __restrict__ a2,       // stage-2 A-frags [30][64][8]
    const f16* __restrict__ a3,       // stage-3 A-frags [30][64][8]
    const float* __restrict__ z,
    const float* __restrict__ b1, const float* __restrict__ b2,
    const float* __restrict__ b3,
    const float* __restrict__ Wh, const float* __restrict__ bh,
    float* __restrict__ part)         // [30][512][10]
{
  const int tid = threadIdx.x;
  // XCD-bijective swizzle: 4096 = 8 XCDs x 512. All 8 same-b groups (and 64
  // consecutive b's) land on one XCD -> x row lives in that XCD's L2.
  const int swz = ((blockIdx.x & 7) * 512) + (blockIdx.x >> 3);
  const int b   = swz >> 3;           // 0..511
  const int G   = swz & 7;            // d-quad group: d = 4G .. 4G+3 (G=7: pair)
  const int d_base = 4 * G;

  // LDS: 4 regions x 8192 f16 = 65536B exactly.
  //   region g: h1 f16[4 rows][512 chunks(f16x4)]  (rotated: slot=(p+5r)&511)
  //             overlaid by h2 f16[8 rows][512 dwords] (same rotation)
  //   red[4][32] floats overlays region 0 after the post-stage-3 barrier.
  __shared__ __align__(16) f16 smemh[32768];
  float* red = (float*)smemh;

  const int w = tid >> 6, lane = tid & 63, quad = lane >> 4, n = lane & 15;
  const int gg = w >> 2, wv = w & 3;  // wave-group (d within quad), wave-in-group
  const int d  = d_base + gg;
  const int dc = d < 30 ? d : 29;     // clamp for tail group's dead waves

  // ---- stage 1 (MFMA, ALL 16 waves, 4 d's): 128 tiles of 16 positions ----
  // A = patches: lane(row=n, kg=quad) holds x[e=2q..2q+1][2*pos + 0..3],
  //   pos = 16t + n; tap-3 K-slots hit zero weights (x finite, no masking).
  // B = a1q (cols 0-15 = 4d x 4ch). D: lane(col=n, quad) holds positions
  //   16t+4*quad+0..3 of (region = n>>2, row = n&3); one rotated b64 write.
  // Position 2047 tail is garbage-finite (feeds only masked jl=1023 col).
  {
    const f16x8 bw1 = *(const f16x8*)(a1q + ((size_t)G * 64 + lane) * 8);
    const int dn  = d_base + (n >> 2);
    const int dnc = dn < 30 ? dn : 29;
    const float bias = b1[dnc * 4 + (n & 3)];
    const f32x4 c1i = {bias, bias, bias, bias};
    const char* xc = (const char*)x + (size_t)b * 65536 + quad * 16384 + 4 * n;
    f16x4* h1c = (f16x4*)smemh + (n >> 2) * 2048 + (n & 3) * 512;
    const int rot1 = 5 * (n & 3);
    #pragma unroll
    for (int i = 0; i < 8; ++i) {
      const int t = w + 16 * i;                // 0..127
      const uint32_t o = 64u * (uint32_t)t;
      union { f16x8 v; uint32_t dw[4]; } u;
      u.dw[0] = *(const uint32_t*)(xc + o);            // e0: taps 0,1
      u.dw[1] = *(const uint32_t*)(xc + o + 4);        // e0: tap 2 (+dead)
      u.dw[2] = *(const uint32_t*)(xc + o + 8192);     // e1: taps 0,1
      u.dw[3] = *(const uint32_t*)(xc + o + 8192 + 4); // e1: tap 2 (+dead)
      const f32x4 D = __builtin_amdgcn_mfma_f32_16x16x32_f16(u.v, bw1, c1i, 0, 0, 0);
      f16x4 p;
      p.x = (f16)fmaxf(D[0], 0.0f); p.y = (f16)fmaxf(D[1], 0.0f);
      p.z = (f16)fmaxf(D[2], 0.0f); p.w = (f16)fmaxf(D[3], 0.0f);
      const int slot = (4 * t + quad + rot1) & 511;
      h1c[slot] = p;                           // ds_write_b64, rotated
    }
  }
  __syncthreads();

  // ---- stage 2 (MFMA): wave-group gg handles d on region gg; 32 tiles ----
  // B-frag = h1[row=quad][chunks 16t+n, 16t+n+1] (rotated). The +1 wrap at
  // chunk 512 aliases chunk 0 (finite; feeds only zero-weight K-slots or
  // the masked jl=1023 column).
  f32x4 Ci[8];
  {
    const f16x8 af2 = *(const f16x8*)(a2 + ((size_t)dc * 64 + lane) * 8);
    const f32x4 cinit2 = *(const f32x4*)(b2 + dc * 8 + (quad & 1) * 4);
    const f16x4* h1r = (const f16x4*)smemh + gg * 2048 + quad * 512;
    const int rot2 = 5 * quad;
    #pragma unroll
    for (int i = 0; i < 8; ++i) {
      const int t = wv + 4 * i;               // 0..31
      const int base = 16 * t + n;
      const f16x4 lo = h1r[(base + rot2) & 511];
      const f16x4 hi = h1r[(base + 1 + rot2) & 511];
      const f16x8 bv = __builtin_shufflevector(lo, hi, 0, 1, 2, 3, 4, 5, 6, 7);
      Ci[i] = __builtin_amdgcn_mfma_f32_16x16x32_f16(af2, bv, cinit2, 0, 0, 0);
    }
  }
  __syncthreads();               // all h1 reads done; overlay h2 per region

  // ---- h2 write: rows 0-7 = c2 @ dword 16t+n (rotated), byte = shift ----
  {
    f16* h2b = smemh + gg * 8192;
    const int shift = quad >> 1;             // byte within dword
    const int c2b   = (quad & 1) * 4;
    #pragma unroll
    for (int i = 0; i < 8; ++i) {
      const int t  = wv + 4 * i;
      const int dw = 16 * t + n;             // dword col 0..511
      #pragma unroll
      for (int r = 0; r < 4; ++r) {
        const int row  = c2b + r;
        const int slot = (dw + 5 * row) & 511;
        h2b[row * 1024 + slot * 2 + shift] = (f16)fmaxf(Ci[i][r], 0.0f);
      }
    }
  }
  __syncthreads();

  // ---- stage 3 (MFMA) + pool: wave-group gg on region gg; 32 tiles ----
  // Reads rows c2a, c2a+1 at dwords dw, dw+1 (rotated; dw+1 wrap feeds only
  // masked outputs p>=1021).
  float pool4[4] = {0.0f, 0.0f, 0.0f, 0.0f};
  {
    const f16x8 af3 = *(const f16x8*)(a3 + ((size_t)dc * 64 + lane) * 8);
    const f32x4 cinit3 = *(const f32x4*)(b3 + dc * 8 + (quad & 1) * 4);
    const f16* h2r = smemh + gg * 8192;
    const int c2a = quad * 2;
    const int rotA = 5 * c2a, rotB = 5 * (c2a + 1);
    #pragma unroll
    for (int i = 0; i < 8; ++i) {
      const int t  = wv + 4 * i;              // 0..31
      const int dw = 16 * t + n;
      union { f16x8 v; f16x2 q[4]; } u;
      u.q[0] = *(const f16x2*)(h2r + c2a * 1024       + 2 * ((dw     + rotA) & 511));
      u.q[1] = *(const f16x2*)(h2r + c2a * 1024       + 2 * ((dw + 1 + rotA) & 511));
      u.q[2] = *(const f16x2*)(h2r + (c2a + 1) * 1024 + 2 * ((dw     + rotB) & 511));
      u.q[3] = *(const f16x2*)(h2r + (c2a + 1) * 1024 + 2 * ((dw + 1 + rotB) & 511));
      const f32x4 C = __builtin_amdgcn_mfma_f32_16x16x32_f16(af3, u.v, cinit3, 0, 0, 0);
      const int pl = 32 * t + 2 * n + (quad >> 1);
      if (pl < 1021) {
        #pragma unroll
        for (int r = 0; r < 4; ++r) pool4[r] += fmaxf(C[r], 0.0f);
      }
    }
  }
  __syncthreads();               // stage-3 LDS reads done -> red may overlay

  // ---- pool reduction: shfl_xor butterfly over the 32 lanes sharing a
  //   cc-group (masks 1,2,4,8,32 never touch lane bit 4), one write per
  //   (wave, cc-group) into red[gg][32] (overlay on region 0).
  {
    #pragma unroll
    for (int r = 0; r < 4; ++r) pool4[r] += __shfl_xor(pool4[r], 1, 64);
    #pragma unroll
    for (int r = 0; r < 4; ++r) pool4[r] += __shfl_xor(pool4[r], 2, 64);
    #pragma unroll
    for (int r = 0; r < 4; ++r) pool4[r] += __shfl_xor(pool4[r], 4, 64);
    #pragma unroll
    for (int r = 0; r < 4; ++r) pool4[r] += __shfl_xor(pool4[r], 8, 64);
    #pragma unroll
    for (int r = 0; r < 4; ++r) pool4[r] += __shfl_xor(pool4[r], 32, 64);
    if ((lane & 47) == 0) {      // lanes 0 (cc 0-3) and 16 (cc 4-7)
      const int cg = (lane >> 4) & 1;
      #pragma unroll
      for (int r = 0; r < 4; ++r)
        red[gg * 32 + wv * 8 + cg * 4 + r] = pool4[r];
    }
  }
  __syncthreads();

  // ---- heads: waves 0,4,8,12 -> d = d_base + gg (guard d<30) ----
  if ((w & 3) == 0 && lane < 10 && d < 30) {
    float acc = bh[d * 10 + lane];
    #pragma unroll
    for (int c3 = 0; c3 < 8; ++c3) {
      const float pooled = red[gg * 32 + c3]      + red[gg * 32 + 8 + c3]
                         + red[gg * 32 + 16 + c3] + red[gg * 32 + 24 + c3];
      acc = fmaf(pooled * (1.0f / 1021.0f), Wh[d * 80 + lane * 8 + c3], acc);
    }
    part[((size_t)d * 512 + b) * 10 + lane] = z[d] * acc;
  }
}

// Fixed-order reduction over 30 d-partials: bitwise-deterministic.
__global__ __launch_bounds__(256) void reduce30_kernel(
    const float* __restrict__ part,   // [30][512][10]
    float* __restrict__ out)          // [512][10]
{
  const int i = blockIdx.x * 256 + threadIdx.x;   // 0..5119
  float s = 0.0f;
  #pragma unroll
  for (int dd = 0; dd < 30; ++dd) s += part[dd * 5120 + i];
  out[i] = s;
}

// ---------------- fallback path: exact R7 fp32 kernel (60 partials) ----------------
__global__ __launch_bounds__(256, 6) void ensemble_kernel(
    const int* __restrict__ ids, const float* __restrict__ mask,
    const float* __restrict__ z, const float* __restrict__ tbl,
    const float* __restrict__ W1, const float* __restrict__ b1,
    const float* __restrict__ W2, const float* __restrict__ b2,
    const float* __restrict__ W3, const float* __restrict__ b3,
    const float* __restrict__ Wh, const float* __restrict__ bh,
    float* __restrict__ part)
{
  const int tid  = threadIdx.x;
  const int half = blockIdx.x & 1;
  const int bd   = blockIdx.x >> 1;
  const int b    = bd & 511;
  const int d    = bd >> 9;

  __shared__ float smem[4128];
  __shared__ float red[32];
  __shared__ float pooled[8];

  const int l_lo = half ? 1024 : 0;
  const int l_hi = half ? 2047 : 1029;
  const int j_lo = half ? 512  : 0;
  const int j_hi = half ? 1023 : 514;
  const int o_lo = half ? 512  : 0;
  const int o_hi = half ? 1021 : 512;

  const int*    idrow = ids  + (size_t)b * 4096;
  const float*  mrow  = mask + (size_t)b * 4096;
  const float4* tbl4  = (const float4*)tbl;
  const float*  w1p = W1 + d * 96;
  const float*  w2p = W2 + d * 96;
  const float*  w3p = W3 + d * 192;

  {
    float bia[4];
    #pragma unroll
    for (int c = 0; c < 4; ++c) bia[c] = b1[d * 4 + c];

    #pragma unroll 1
    for (int pass = 0; pass < 2; ++pass) {
      const int l0 = l_lo + 2 * tid + 512 * pass;
      const int p0 = 2 * l0;
      const int4   iv = *(const int4*)(idrow + p0);
      const float4 mv = *(const float4*)(mrow + p0);
      int i4; float m4;
      if (p0 + 4 < 4096) { i4 = idrow[p0 + 4]; m4 = mrow[p0 + 4]; }
      else               { i4 = 0;              m4 = 0.0f; }

      const int   pid[5] = {iv.x, iv.y, iv.z, iv.w, i4};
      const float pm[5]  = {mv.x, mv.y, mv.z, mv.w, m4};

      float a0[4], a1v[4];
      #pragma unroll
      for (int c = 0; c < 4; ++c) { a0[c] = bia[c]; a1v[c] = bia[c]; }

      #pragma unroll
      for (int q = 0; q < 5; ++q) {
        const float4 va = tbl4[(size_t)pid[q] * 2];
        const float4 vb = tbl4[(size_t)pid[q] * 2 + 1];
        const float xe[8] = {va.x * pm[q], va.y * pm[q], va.z * pm[q], va.w * pm[q],
                             vb.x * pm[q], vb.y * pm[q], vb.z * pm[q], vb.w * pm[q]};
        if (q <= 2) {
          #pragma unroll
          for (int c = 0; c < 4; ++c)
            #pragma unroll
            for (int e = 0; e < 8; ++e)
              a0[c] = fmaf(xe[e], w1p[c * 24 + e * 3 + q], a0[c]);
        }
        if (q >= 2) {
          #pragma unroll
          for (int c = 0; c < 4; ++c)
            #pragma unroll
            for (int e = 0; e < 8; ++e)
              a1v[c] = fmaf(xe[e], w1p[c * 24 + e * 3 + (q - 2)], a1v[c]);
        }
      }
      const int rel = l0 - l_lo;
      if (l0 + 1 < l_hi) {
        #pragma unroll
        for (int c = 0; c < 4; ++c)
          *(float2*)(smem + c * 1032 + rel) =
              make_float2(fmaxf(a0[c], 0.0f), fmaxf(a1v[c], 0.0f));
      } else if (l0 < l_hi) {
        #pragma unroll
        for (int c = 0; c < 4; ++c)
          smem[c * 1032 + rel] = fmaxf(a0[c], 0.0f);
      }
    }
    const int lt = l_lo + 1024 + tid;
    if (lt < l_hi) {
      float a0[4];
      #pragma unroll
      for (int c = 0; c < 4; ++c) a0[c] = bia[c];
      #pragma unroll
      for (int k = 0; k < 3; ++k) {
        const int p = 2 * lt + k;
        const int id = idrow[p];
        const float m = mrow[p];
        const float4 va = tbl4[(size_t)id * 2];
        const float4 vb = tbl4[(size_t)id * 2 + 1];
        const float xe[8] = {va.x*m, va.y*m, va.z*m, va.w*m,
                             vb.x*m, vb.y*m, vb.z*m, vb.w*m};
        #pragma unroll
        for (int cc = 0; cc < 4; ++cc)
          #pragma unroll
          for (int e = 0; e < 8; ++e)
            a0[cc] = fmaf(xe[e], w1p[cc * 24 + e * 3 + k], a0[cc]);
      }
      #pragma unroll
      for (int c = 0; c < 4; ++c)
        smem[c * 1032 + 1024 + tid] = fmaxf(a0[c], 0.0f);
    }
  }
  __syncthreads();

  float acc2[8][2], acc2t[8];
  {
    #pragma unroll
    for (int c2 = 0; c2 < 8; ++c2) {
      const float bb = b2[d * 8 + c2];
      acc2[c2][0] = bb; acc2[c2][1] = bb; acc2t[c2] = bb;
    }
    const int rel2  = 4 * tid;
    const bool tail2 = tid < (j_hi - j_lo - 512);
    #pragma unroll 1
    for (int c1 = 0; c1 < 4; ++c1) {
      float sw[8][3];
      #pragma unroll
      for (int c2 = 0; c2 < 8; ++c2)
        #pragma unroll
        for (int kk = 0; kk < 3; ++kk)
          sw[c2][kk] = w2p[c2 * 12 + c1 * 3 + kk];
      const float* hp = smem + c1 * 1032;
      const float4 h01 = *(const float4*)(hp + rel2);
      const float  h4v = hp[rel2 + 4];
      #pragma unroll
      for (int c2 = 0; c2 < 8; ++c2) {
        acc2[c2][0] = fmaf(h01.x, sw[c2][0], fmaf(h01.y, sw[c2][1],
                      fmaf(h01.z, sw[c2][2], acc2[c2][0])));
        acc2[c2][1] = fmaf(h01.z, sw[c2][0], fmaf(h01.w, sw[c2][1],
                      fmaf(h4v,   sw[c2][2], acc2[c2][1])));
      }
      if (tail2) {
        const float t0 = hp[1024 + 2 * tid], t1 = hp[1025 + 2 * tid],
                    t2 = hp[1026 + 2 * tid];
        #pragma unroll
        for (int c2 = 0; c2 < 8; ++c2)
          acc2t[c2] = fmaf(t0, sw[c2][0], fmaf(t1, sw[c2][1],
                      fmaf(t2, sw[c2][2], acc2t[c2])));
      }
    }
    #pragma unroll
    for (int c2 = 0; c2 < 8; ++c2) {
      acc2[c2][0] = fmaxf(acc2[c2][0], 0.0f);
      acc2[c2][1] = fmaxf(acc2[c2][1], 0.0f);
      acc2t[c2]   = fmaxf(acc2t[c2],   0.0f);
    }
    __syncthreads();
    const int j0 = j_lo + 2 * tid;
    const int jr = 2 * tid;
    if (j0 + 1 < j_hi) {
      #pragma unroll
      for (int c2 = 0; c2 < 8; ++c2)
        *(float2*)(smem + c2 * 516 + jr) = make_float2(acc2[c2][0], acc2[c2][1]);
    } else if (j0 < j_hi) {
      #pragma unroll
      for (int c2 = 0; c2 < 8; ++c2)
        smem[c2 * 516 + jr] = acc2[c2][0];
    }
    if (tid < (j_hi - j_lo - 512)) {
      #pragma unroll
      for (int c2 = 0; c2 < 8; ++c2)
        smem[c2 * 516 + 512 + tid] = acc2t[c2];
    }
  }
  __syncthreads();

  float acc3[8][2];
  #pragma unroll
  for (int cc = 0; cc < 8; ++cc) {
    const float bb = b3[d * 8 + cc];
    acc3[cc][0] = bb; acc3[cc][1] = bb;
  }
  {
    const int rel3 = 2 * tid;
    #pragma unroll 1
    for (int c2 = 0; c2 < 8; ++c2) {
      float sw[8][3];
      #pragma unroll
      for (int cc = 0; cc < 8; ++cc)
        #pragma unroll
        for (int kk = 0; kk < 3; ++kk)
          sw[cc][kk] = w3p[cc * 24 + c2 * 3 + kk];
      const float* hp = smem + c2 * 516;
      const float2 ha = *(const float2*)(hp + rel3);
      const float2 hb = *(const float2*)(hp + rel3 + 2);
      #pragma unroll
      for (int cc = 0; cc < 8; ++cc) {
        acc3[cc][0] = fmaf(ha.x, sw[cc][0], fmaf(ha.y, sw[cc][1],
                      fmaf(hb.x, sw[cc][2], acc3[cc][0])));
        acc3[cc][1] = fmaf(ha.y, sw[cc][0], fmaf(hb.x, sw[cc][1],
                      fmaf(hb.y, sw[cc][2], acc3[cc][1])));
      }
    }
  }
  const int i0 = o_lo + 2 * tid;
  float psum[8];
  #pragma unroll
  for (int cc = 0; cc < 8; ++cc) {
    float s = 0.0f;
    if (i0 < o_hi)     s += fmaxf(acc3[cc][0], 0.0f);
    if (i0 + 1 < o_hi) s += fmaxf(acc3[cc][1], 0.0f);
    psum[cc] = s;
  }

  const int lane = tid & 63;
  const int wid  = tid >> 6;
  #pragma unroll
  for (int c = 0; c < 8; ++c) {
    float v = psum[c];
    #pragma unroll
    for (int off = 32; off > 0; off >>= 1) v += __shfl_down(v, off, 64);
    if (lane == 0) red[wid * 8 + c] = v;
  }
  __syncthreads();
  if (tid < 8)
    pooled[tid] = red[tid] + red[8 + tid] + red[16 + tid] + red[24 + tid];
  __syncthreads();

  if (tid < 10) {
    float acc = (half == 0) ? bh[d * 10 + tid] : 0.0f;
    #pragma unroll
    for (int c3 = 0; c3 < 8; ++c3)
      acc = fmaf(pooled[c3] * (1.0f / 1021.0f), Wh[d * 80 + tid * 8 + c3], acc);
    part[(((size_t)d * 2 + half) * 512 + b) * 10 + tid] = z[d] * acc;
  }
}

__global__ __launch_bounds__(256) void reduce60_kernel(
    const float* __restrict__ part,   // [60][512][10]
    float* __restrict__ out)          // [512][10]
{
  const int i = blockIdx.x * 256 + threadIdx.x;
  float s = 0.0f;
  #pragma unroll
  for (int dd = 0; dd < 60; ++dd) s += part[dd * 5120 + i];
  out[i] = s;
}

extern "C" void kernel_launch(void* const* d_in, const int* in_sizes, int n_in,
                              void* d_out, int out_size, void* d_ws, size_t ws_size,
                              hipStream_t stream) {
  const int*   ids  = (const int*)d_in[0];
  const float* mask = (const float*)d_in[1];
  const float* z    = (const float*)d_in[2];
  const float* tbl  = (const float*)d_in[3];
  const float* W1   = (const float*)d_in[4];
  const float* b1   = (const float*)d_in[5];
  const float* W2   = (const float*)d_in[6];
  const float* b2   = (const float*)d_in[7];
  const float* W3   = (const float*)d_in[8];
  const float* b3   = (const float*)d_in[9];
  const float* Wh   = (const float*)d_in[10];
  const float* bh   = (const float*)d_in[11];
  float* out  = (float*)d_out;
  float* part = (float*)d_ws;

  // Layout: part | x | a1q | a2 | a3.  x sits BEFORE the small weight arrays
  // so stage-1's 8-byte tail over-read (b=511,e=7,pos=2047) lands in a1q
  // (allocated, finite) instead of past the workspace.
  const size_t part_bytes = 1228800;                       // max(30,60)-layout
  const size_t x_bytes    = (size_t)512 * 8 * 4096 * 2;    // 32 MiB f16
  const size_t a1_bytes   = 8192;                          // [8][64][8] f16
  const size_t a_bytes    = 30720;                         // [30][64][8] f16
  const size_t need = part_bytes + x_bytes + a1_bytes + 2 * a_bytes;

  if (ws_size >= need) {
    f16* xh  = (f16*)((char*)d_ws + part_bytes);
    f16* a1q = (f16*)((char*)d_ws + part_bytes + x_bytes);
    f16* a2  = (f16*)((char*)d_ws + part_bytes + x_bytes + a1_bytes);
    f16* a3  = (f16*)((char*)d_ws + part_bytes + x_bytes + a1_bytes + a_bytes);
    hipLaunchKernelGGL(prep_kernel, dim3(4096 + 17), dim3(256), 0, stream,
                       ids, mask, tbl, W1, W2, W3, xh, a1q, a2, a3);
    hipLaunchKernelGGL(ensemble_f16_kernel, dim3(512 * 8), dim3(1024), 0, stream,
                       xh, a1q, a2, a3, z, b1, b2, b3, Wh, bh, part);
    hipLaunchKernelGGL(reduce30_kernel, dim3(20), dim3(256), 0, stream, part, out);
  } else {
    hipLaunchKernelGGL(ensemble_kernel, dim3(512 * 30 * 2), dim3(256), 0, stream,
                       ids, mask, z, tbl, W1, b1, W2, b2, W3, b3, Wh, bh, part);
    hipLaunchKernelGGL(reduce60_kernel, dim3(20), dim3(256), 0, stream, part, out);
  }
}